// Round 6
// baseline (49.714 us; speedup 1.0000x reference)
//
#include <hip/hip_runtime.h>
#include <math.h>

#define B_TOT 32768
#define DIM   512
#define NS    100
#define NCOL  101
#define TB    128              // rows per block (8 waves x 16 rows)
#define NBLK  (B_TOT / TB)     // 256 blocks = 1/CU
#define WPITCH 520             // bf16 elems per W row: 1040 B; bank stride 4, 2-way max (free)
#define LSCALE 1048576.0f      // 2^20 fixed-point loss scale

typedef __attribute__((ext_vector_type(8))) short short8;   // 8 bf16 (4 VGPRs)
typedef __attribute__((ext_vector_type(4))) float f32x4;    // MFMA accumulator

// fp32 -> bf16 round-to-nearest-even, bit form
static __device__ __forceinline__ short f2bf(float f) {
    unsigned u = __builtin_bit_cast(unsigned, f);
    unsigned r = (u + 0x7FFFu + ((u >> 16) & 1u)) >> 16;
    return (short)r;
}

// Single fused kernel: W-stage + sampled GEMM (MFMA) + true-dot + LSE + deterministic
// fixed-point loss reduction with last-block finalize.
__global__ __launch_bounds__(512)
void fused_kernel(const int* __restrict__ label,
                  const float* __restrict__ inputs,
                  const float* __restrict__ weights,
                  const float* __restrict__ biases,
                  const int* __restrict__ sids,
                  const float* __restrict__ tq,
                  const float* __restrict__ sq,
                  float* __restrict__ out,
                  unsigned long long* __restrict__ acc,
                  unsigned* __restrict__ ticket)
{
    __shared__ short W_lds[112 * WPITCH];   // 116 KB, rows 100-111 unused
    __shared__ float base_lds[112];         // biases[sid] - log(sq), -inf pad
    __shared__ int   s_sid[NS];
    __shared__ float ls_lds[8];             // per-wave loss partials

    const int t = threadIdx.x;

    if (t < NS) s_sid[t] = sids[t];
    __syncthreads();

    // ---- stage sampled W -> bf16 LDS (row layout), fully coalesced float4 reads ----
    for (int idx = t; idx < NS * 128; idx += 512) {
        const int row = idx >> 7;
        const int kq  = (idx & 127) * 4;
        const float4 wv = *(const float4*)(weights + (long)s_sid[row] * DIM + kq);
        *(short4*)&W_lds[row * WPITCH + kq] =
            make_short4(f2bf(wv.x), f2bf(wv.y), f2bf(wv.z), f2bf(wv.w));
    }
    if (t < 112)
        base_lds[t] = (t < NS) ? biases[s_sid[t]] - logf(sq[t]) : -INFINITY;

    const int wave = t >> 6;
    const int lane = t & 63;
    const int rit  = lane & 15;              // A row within tile / C-D col index
    const int seg  = lane >> 4;              // k-segment (8 k each)
    const long b0  = (long)blockIdx.x * TB;
    const long absRow = b0 + wave * 16 + rit;
    const int lab = label[absRow];
    const float* aptr = inputs  + absRow * DIM + seg * 8;
    const float* wtp  = weights + (long)lab * DIM + seg * 8;

    f32x4 acc_r[7];
    #pragma unroll
    for (int c = 0; c < 7; c++) acc_r[c] = (f32x4){0.f, 0.f, 0.f, 0.f};
    float tacc = 0.f;

    __syncthreads();

    // ---- K loop: A-stream + true-W gather from global, B-frags from LDS ----
    #pragma unroll
    for (int kc = 0; kc < DIM / 32; kc++) {
        const int k0 = kc * 32;
        const float4 a0 = *(const float4*)(aptr + k0);
        const float4 a1 = *(const float4*)(aptr + k0 + 4);
        const float4 w0 = *(const float4*)(wtp + k0);
        const float4 w1 = *(const float4*)(wtp + k0 + 4);

        tacc = fmaf(a0.x, w0.x, tacc); tacc = fmaf(a0.y, w0.y, tacc);
        tacc = fmaf(a0.z, w0.z, tacc); tacc = fmaf(a0.w, w0.w, tacc);
        tacc = fmaf(a1.x, w1.x, tacc); tacc = fmaf(a1.y, w1.y, tacc);
        tacc = fmaf(a1.z, w1.z, tacc); tacc = fmaf(a1.w, w1.w, tacc);

        short8 af;
        af[0] = f2bf(a0.x); af[1] = f2bf(a0.y); af[2] = f2bf(a0.z); af[3] = f2bf(a0.w);
        af[4] = f2bf(a1.x); af[5] = f2bf(a1.y); af[6] = f2bf(a1.z); af[7] = f2bf(a1.w);

        const int wko = k0 + seg * 8;
        #pragma unroll
        for (int c = 0; c < 7; c++) {
            const short8 bf = *(const short8*)&W_lds[(c * 16 + rit) * WPITCH + wko];
            acc_r[c] = __builtin_amdgcn_mfma_f32_16x16x32_bf16(af, bf, acc_r[c], 0, 0, 0);
        }
    }

    // ---- true logit: reduce 4 k-segments; every lane gets row (lane&15)'s value ----
    tacc += __shfl_xor(tacc, 16);
    tacc += __shfl_xor(tacc, 32);
    const float tl = tacc + biases[lab] - logf(tq[absRow]);
    if (lane < 16) out[absRow * NCOL] = tl;

    // ---- fused per-row LSE + loss + sampled-logit writes ----
    // C/D layout: col = lane&15 (rit), row = (lane>>4)*4 + reg
    const int g = lane >> 4;
    float base_v[7];
    #pragma unroll
    for (int c = 0; c < 7; c++) base_v[c] = base_lds[c * 16 + rit];

    float loss_sum = 0.f;
    #pragma unroll
    for (int i = 0; i < 4; i++) {
        const int r = g * 4 + i;
        const long orow = (b0 + wave * 16 + r) * NCOL;
        const float tlv = __shfl(tl, r);     // lane r holds row r's true logit
        float v[7];
        float m = tlv;
        #pragma unroll
        for (int c = 0; c < 7; c++) {
            v[c] = acc_r[c][i] + base_v[c];  // base = -inf for pad cols
            m = fmaxf(m, v[c]);
        }
        #pragma unroll
        for (int off = 1; off < 16; off <<= 1) m = fmaxf(m, __shfl_xor(m, off));
        float s = (rit == 0) ? expf(tlv - m) : 0.f;
        #pragma unroll
        for (int c = 0; c < 7; c++) s += expf(v[c] - m);
        #pragma unroll
        for (int off = 1; off < 16; off <<= 1) s += __shfl_xor(s, off);
        loss_sum += m + logf(s) - tlv;
        #pragma unroll
        for (int c = 0; c < 7; c++) {
            const int col = c * 16 + rit;
            if (col < NS) out[orow + 1 + col] = v[c];
        }
    }
    float wl = (rit == 0) ? loss_sum : 0.f;
    wl += __shfl_xor(wl, 16);
    wl += __shfl_xor(wl, 32);
    if (lane == 0) ls_lds[wave] = wl;
    __syncthreads();

    // ---- deterministic loss: fixed-point integer atomic + last-block finalize ----
    if (t == 0) {
        float bp = 0.f;
        #pragma unroll
        for (int w = 0; w < 8; w++) bp += ls_lds[w];
        atomicAdd(acc, (unsigned long long)llrintf(bp * LSCALE));
        __threadfence();                       // release: acc add visible before ticket add
        const unsigned old = atomicAdd(ticket, 1u);
        if (old == NBLK - 1) {
            __threadfence();                   // acquire
            const unsigned long long total = atomicAdd(acc, 0ULL);
            out[(long)B_TOT * NCOL] =
                (float)((double)total * (1.0 / ((double)LSCALE * (double)B_TOT)));
        }
    }
}

extern "C" void kernel_launch(void* const* d_in, const int* in_sizes, int n_in,
                              void* d_out, int out_size, void* d_ws, size_t ws_size,
                              hipStream_t stream)
{
    const int*   label   = (const int*)d_in[0];
    const float* inputs  = (const float*)d_in[1];
    const float* weights = (const float*)d_in[2];
    const float* biases  = (const float*)d_in[3];
    const int*   sids    = (const int*)d_in[4];
    const float* tq      = (const float*)d_in[5];
    const float* sq      = (const float*)d_in[6];
    float* out = (float*)d_out;
    unsigned long long* acc = (unsigned long long*)d_ws;
    unsigned* ticket = (unsigned*)((char*)d_ws + 8);

    hipMemsetAsync(d_ws, 0, 16, stream);   // zero accumulator + ticket (graph memset node)
    fused_kernel<<<NBLK, 512, 0, stream>>>(label, inputs, weights, biases,
                                           sids, tq, sq, out, acc, ticket);
}

// Round 8
// 38.515 us; speedup vs baseline: 1.2908x; 1.2908x over previous
//
#include <hip/hip_runtime.h>
#include <math.h>

#define B_TOT 32768
#define DIM   512
#define NS    100
#define NCOL  101
#define TB    128              // rows per block (8 waves x 16 rows)
#define NBLK  (B_TOT / TB)     // 256 blocks = 1/CU
#define WPITCH 520             // bf16 elems per W row: 1040 B; bank stride 4, 2-way max (free)

typedef __attribute__((ext_vector_type(8))) short short8;   // 8 bf16 (4 VGPRs)
typedef __attribute__((ext_vector_type(4))) float f32x4;    // MFMA accumulator

// fp32 -> bf16 round-to-nearest-even, bit form
static __device__ __forceinline__ short f2bf(float f) {
    unsigned u = __builtin_bit_cast(unsigned, f);
    unsigned r = (u + 0x7FFFu + ((u >> 16) & 1u)) >> 16;
    return (short)r;
}

// Fused: W-stage + sampled GEMM (MFMA) + true-dot (prefetch-ring gather) + LSE.
__global__ __launch_bounds__(512)
void fused_kernel(const int* __restrict__ label,
                  const float* __restrict__ inputs,
                  const float* __restrict__ weights,
                  const float* __restrict__ biases,
                  const int* __restrict__ sids,
                  const float* __restrict__ tq,
                  const float* __restrict__ sq,
                  float* __restrict__ out,
                  float* __restrict__ lpart)
{
    __shared__ short W_lds[112 * WPITCH];   // 116 KB; rows 100-111 ZEROED (pad)
    __shared__ float base_lds[112];         // biases[sid] - log(sq), -inf pad
    __shared__ int   s_sid[NS];
    __shared__ float ls_lds[8];             // per-wave loss partials

    const int t = threadIdx.x;

    if (t < NS) s_sid[t] = sids[t];
    __syncthreads();

    // ---- stage sampled W -> bf16 LDS (row layout), coalesced float4 reads ----
    for (int idx = t; idx < NS * 128; idx += 512) {
        const int row = idx >> 7;
        const int kq  = (idx & 127) * 4;
        const float4 wv = *(const float4*)(weights + (long)s_sid[row] * DIM + kq);
        *(short4*)&W_lds[row * WPITCH + kq] =
            make_short4(f2bf(wv.x), f2bf(wv.y), f2bf(wv.z), f2bf(wv.w));
    }
    // zero pad rows 100-111 (12 rows x WPITCH shorts) -> pad MFMA results exactly 0
    for (int idx = t; idx < 12 * (WPITCH / 4); idx += 512) {
        const int row = 100 + idx / (WPITCH / 4);
        const int kq  = (idx % (WPITCH / 4)) * 4;
        *(short4*)&W_lds[row * WPITCH + kq] = make_short4(0, 0, 0, 0);
    }
    if (t < 112)
        base_lds[t] = (t < NS) ? biases[s_sid[t]] - logf(sq[t]) : -INFINITY;

    const int wave = t >> 6;
    const int lane = t & 63;
    const int rit  = lane & 15;              // A row within tile / C-D col index
    const int seg  = lane >> 4;              // k-segment (8 k each)
    const long b0  = (long)blockIdx.x * TB;
    const long absRow = b0 + wave * 16 + rit;
    const int lab = label[absRow];
    const float* aptr = inputs  + absRow * DIM + seg * 8;
    const float* wtp  = weights + (long)lab * DIM + seg * 8;

    f32x4 acc_r[7];
    #pragma unroll
    for (int c = 0; c < 7; c++) acc_r[c] = (f32x4){0.f, 0.f, 0.f, 0.f};

    // ---- prefetch rings: A depth 4, true-W gather depth 8 ----
    float4 ar[4][2];
    float4 wr[8][2];
    #pragma unroll
    for (int p = 0; p < 4; p++) {
        ar[p][0] = *(const float4*)(aptr + p * 32);
        ar[p][1] = *(const float4*)(aptr + p * 32 + 4);
    }
    #pragma unroll
    for (int p = 0; p < 8; p++) {
        wr[p][0] = *(const float4*)(wtp + p * 32);
        wr[p][1] = *(const float4*)(wtp + p * 32 + 4);
    }

    __syncthreads();   // W_lds ready

    float t0 = 0.f, t1 = 0.f;
    #pragma unroll
    for (int kc = 0; kc < 16; kc++) {
        const int sa = kc & 3, sw = kc & 7;
        const float4 a0 = ar[sa][0], a1 = ar[sa][1];
        const float4 w0 = wr[sw][0], w1 = wr[sw][1];
        if (kc + 4 < 16) {
            ar[sa][0] = *(const float4*)(aptr + (kc + 4) * 32);
            ar[sa][1] = *(const float4*)(aptr + (kc + 4) * 32 + 4);
        }
        if (kc + 8 < 16) {
            wr[sw][0] = *(const float4*)(wtp + (kc + 8) * 32);
            wr[sw][1] = *(const float4*)(wtp + (kc + 8) * 32 + 4);
        }

        // true-dot: two independent fp32 chains
        t0 = fmaf(a0.x, w0.x, t0); t0 = fmaf(a0.y, w0.y, t0);
        t0 = fmaf(a0.z, w0.z, t0); t0 = fmaf(a0.w, w0.w, t0);
        t1 = fmaf(a1.x, w1.x, t1); t1 = fmaf(a1.y, w1.y, t1);
        t1 = fmaf(a1.z, w1.z, t1); t1 = fmaf(a1.w, w1.w, t1);

        short8 af;
        af[0] = f2bf(a0.x); af[1] = f2bf(a0.y); af[2] = f2bf(a0.z); af[3] = f2bf(a0.w);
        af[4] = f2bf(a1.x); af[5] = f2bf(a1.y); af[6] = f2bf(a1.z); af[7] = f2bf(a1.w);

        const int wko = kc * 32 + seg * 8;
        #pragma unroll
        for (int c = 0; c < 7; c++) {
            const short8 bf = *(const short8*)&W_lds[(c * 16 + rit) * WPITCH + wko];
            acc_r[c] = __builtin_amdgcn_mfma_f32_16x16x32_bf16(af, bf, acc_r[c], 0, 0, 0);
        }
    }
    float tacc = t0 + t1;

    // ---- true logit: reduce 4 k-segments; every lane gets row (lane&15)'s value ----
    tacc += __shfl_xor(tacc, 16);
    tacc += __shfl_xor(tacc, 32);
    const float tl = tacc + biases[lab] - logf(tq[absRow]);
    if (lane < 16) out[absRow * NCOL] = tl;

    // ---- fused per-row LSE + loss + sampled-logit writes ----
    // C/D layout: col = lane&15 (rit), row = (lane>>4)*4 + reg
    const int g = lane >> 4;
    float base_v[7];
    #pragma unroll
    for (int c = 0; c < 7; c++) base_v[c] = base_lds[c * 16 + rit];

    float loss_sum = 0.f;
    #pragma unroll
    for (int i = 0; i < 4; i++) {
        const int r = g * 4 + i;
        const long orow = (b0 + wave * 16 + r) * NCOL;
        const float tlv = __shfl(tl, r);     // lane r holds row r's true logit
        float v[7];
        float m = tlv;
        #pragma unroll
        for (int c = 0; c < 7; c++) {
            v[c] = acc_r[c][i] + base_v[c];  // pad cols: 0 + (-inf) = -inf exactly
            m = fmaxf(m, v[c]);
        }
        #pragma unroll
        for (int off = 1; off < 16; off <<= 1) m = fmaxf(m, __shfl_xor(m, off));
        float s = (rit == 0) ? expf(tlv - m) : 0.f;
        #pragma unroll
        for (int c = 0; c < 7; c++) s += expf(v[c] - m);
        #pragma unroll
        for (int off = 1; off < 16; off <<= 1) s += __shfl_xor(s, off);
        loss_sum += m + logf(s) - tlv;
        #pragma unroll
        for (int c = 0; c < 7; c++) {
            const int col = c * 16 + rit;
            if (col < NS) out[orow + 1 + col] = v[c];
        }
    }
    float wl = (rit == 0) ? loss_sum : 0.f;
    wl += __shfl_xor(wl, 16);
    wl += __shfl_xor(wl, 32);
    if (lane == 0) ls_lds[wave] = wl;
    __syncthreads();
    if (t == 0) {
        float bp = 0.f;
        #pragma unroll
        for (int w = 0; w < 8; w++) bp += ls_lds[w];
        lpart[blockIdx.x] = bp;
    }
}

// deterministic tree reduce of 256 block partials in double -> mean loss
__global__ __launch_bounds__(256)
void reduce_kernel(const float* __restrict__ lpart, float* __restrict__ out_loss)
{
    __shared__ double buf[256];
    buf[threadIdx.x] = (double)lpart[threadIdx.x];
    __syncthreads();
    for (int o = 128; o > 0; o >>= 1) {
        if (threadIdx.x < o) buf[threadIdx.x] += buf[threadIdx.x + o];
        __syncthreads();
    }
    if (threadIdx.x == 0) *out_loss = (float)(buf[0] * (1.0 / (double)B_TOT));
}

extern "C" void kernel_launch(void* const* d_in, const int* in_sizes, int n_in,
                              void* d_out, int out_size, void* d_ws, size_t ws_size,
                              hipStream_t stream)
{
    const int*   label   = (const int*)d_in[0];
    const float* inputs  = (const float*)d_in[1];
    const float* weights = (const float*)d_in[2];
    const float* biases  = (const float*)d_in[3];
    const int*   sids    = (const int*)d_in[4];
    const float* tq      = (const float*)d_in[5];
    const float* sq      = (const float*)d_in[6];
    float* out   = (float*)d_out;
    float* lpart = (float*)d_ws;   // 256 floats

    fused_kernel<<<NBLK, 512, 0, stream>>>(label, inputs, weights, biases,
                                           sids, tq, sq, out, lpart);
    reduce_kernel<<<1, 256, 0, stream>>>(lpart, out + (long)B_TOT * NCOL);
}